// Round 10
// baseline (122.083 us; speedup 1.0000x reference)
//
#include <hip/hip_runtime.h>

#define EPSF 1e-10f
#define KPN 32
#define HH 96
#define WW 96
#define NPIX (HH*WW)     // 9216
#define CH 3
#define SH 128
#define SW 128
#define NIMG 64

__device__ inline float wred_sum(float v){
  #pragma unroll
  for(int off=32; off; off>>=1) v += __shfl_xor(v, off, 64);
  return v;
}
__device__ inline float wred_max(float v){
  #pragma unroll
  for(int off=32; off; off>>=1) v = fmaxf(v, __shfl_xor(v, off, 64));
  return v;
}

// ---------------- resize: jax.image.resize bilinear, antialias=True, 128->96 ----------------
__global__ __launch_bounds__(256) void k_resize(const float* __restrict__ img, float* __restrict__ out){
  int idx = blockIdx.x*256 + threadIdx.x;
  if (idx >= NIMG*CH*NPIX) return;
  int ox = idx % WW;
  int oy = (idx / WW) % HH;
  int nc = idx / NPIX;
  float xs = (ox + 0.5f)*(4.0f/3.0f) - 0.5f;
  float ys = (oy + 0.5f)*(4.0f/3.0f) - 0.5f;
  int jx0 = (int)ceilf(xs - 4.0f/3.0f);
  int jy0 = (int)ceilf(ys - 4.0f/3.0f);
  float wx[3], wy[3]; float sx=0.f, sy=0.f;
  #pragma unroll
  for(int t=0;t<3;t++){
    int j = jx0+t;
    float w = 1.0f - 0.75f*fabsf((float)j - xs);
    w = (j>=0 && j<SW) ? fmaxf(w,0.0f) : 0.0f;
    wx[t]=w; sx+=w;
    j = jy0+t;
    w = 1.0f - 0.75f*fabsf((float)j - ys);
    w = (j>=0 && j<SH) ? fmaxf(w,0.0f) : 0.0f;
    wy[t]=w; sy+=w;
  }
  float inv = 1.0f/(sx*sy);
  const float* base = img + (size_t)nc*SH*SW;
  float acc=0.f;
  #pragma unroll
  for(int ty=0;ty<3;ty++){
    if (wy[ty]==0.f) continue;
    int jy = min(max(jy0+ty,0), SH-1);
    #pragma unroll
    for(int tx=0;tx<3;tx++){
      if (wx[tx]==0.f) continue;
      int jx = min(max(jx0+tx,0), SW-1);
      acc += wy[ty]*wx[tx]*base[jy*SW+jx];
    }
  }
  out[idx] = acc*inv;
}

// ---------------- local entropy ----------------
// Channel-split (grid z = ch). Thread: 2x1 outputs (row pair of columns),
// 3x4 reg halo. VGPR ~40 -> 8 waves/SIMD eligible; 13824 waves total so
// occupancy caps at HW limit (R8's 2x2 tile sat at VGPR=128 -> 4/SIMD).
// Direct per-bin evaluation (independent exps -> ILP). OOB sentinel 1e4.
__global__ __launch_bounds__(256) void k_entropy(const float* __restrict__ rimg, float* __restrict__ ent){
  int tid = threadIdx.x;
  int n = blockIdx.y;
  int ch = blockIdx.z;
  int idx = blockIdx.x*256 + tid;    // 0..4607 = pair index
  int row = idx / 48;
  int c0 = (idx % 48)*2;
  const float* src = rimg + ((size_t)(n*CH+ch))*NPIX;
  float v[3][4];
  #pragma unroll
  for (int r=0;r<3;r++){
    int gr = row-1+r;
    bool rok = (gr>=0 && gr<HH);
    #pragma unroll
    for (int c=0;c<4;c++){
      int gc = c0-1+c;
      v[r][c] = (rok && gc>=0 && gc<WW) ? src[gr*96+gc] : 1e4f;
    }
  }
  float S0=0.f,S1=0.f,T0=0.f,T1=0.f;
  #pragma unroll
  for (int b=0;b<16;b++){
    float cb = (float)b * (1.0f/15.0f);
    float cs[4];
    #pragma unroll
    for (int c=0;c<4;c++){
      float d0 = v[0][c]-cb, d1 = v[1][c]-cb, d2 = v[2][c]-cb;
      cs[c] = __expf(-50.f*d0*d0) + __expf(-50.f*d1*d1) + __expf(-50.f*d2*d2);
    }
    float p0 = (cs[0]+cs[1]+cs[2])*(1.f/9.f);
    float p1 = (cs[1]+cs[2]+cs[3])*(1.f/9.f);
    S0 += p0; T0 += p0*__logf(p0+EPSF);
    S1 += p1; T1 += p1*__logf(p1+EPSF);
  }
  float Sa = S0+EPSF, Sb = S1+EPSF;
  float e0 = (__logf(Sa) - T0/Sa)*(1.f/3.f);
  float e1 = (__logf(Sb) - T1/Sb)*(1.f/3.f);
  float* dst = ent + (size_t)n*NPIX + (size_t)row*96 + c0;
  atomicAdd(dst,   e0);
  atomicAdd(dst+1, e1);
}

// ---------------- main gaussians pass ----------------
// s-split (block per (tile, n)): 18 waves/CU. R8/R9: compiler sinks loads
// into compute (~2-3 in flight, latency-bound at 1.3 TB/s). Fix: pin the
// schedule with sched_group_barrier — {16 VMEM_READ} groups alternating
// with {256 VALU} groups keeps 16-32 loads in flight. Perf-only directive,
// no correctness impact. Masks: VMEM_READ=0x20, VALU=0x2.
// mi folded: mi = re + min((1-ah)*(K - se*sh), 0), K = relu(se-re);
// the 32*re term is recovered in k_final from reS.
__global__ __launch_bounds__(256) void k_main(const float* __restrict__ gauss,
                                              const float* __restrict__ status,
                                              const float* __restrict__ ent,
                                              float* __restrict__ miS,
                                              float* __restrict__ melN,
                                              float* __restrict__ mcelN,
                                              float* __restrict__ reS,
                                              float* __restrict__ ceS,
                                              unsigned int* __restrict__ gmax,
                                              float* __restrict__ hsG){
  __shared__ float stc[32], stq[32];
  int tid = threadIdx.x;
  int lane = tid & 63;
  int tile = blockIdx.x;   // 0..17
  int n = blockIdx.y;      // 0..63 = b*4+s
  int s = n & 3;
  int np = (s==0) ? n+3 : n-1;
  bool nz = (n==0);
  if (tid < 32) stc[tid] = status[n*32 + tid];
  else if (tid < 64) stq[tid-32] = status[np*32 + (tid-32)];
  __syncthreads();
  unsigned off = (unsigned)(tile*256 + tid);     // float2 index within a plane
  const float2* __restrict__ gcp = (const float2*)gauss + (size_t)n*32*4608 + off;
  const float2* __restrict__ gqp = (const float2*)gauss + (size_t)np*32*4608 + off;
  const float2* __restrict__ e2 = (const float2*)ent;
  float2 re2 = e2[(size_t)n*4608 + off];
  float2 se2 = e2[(size_t)np*4608 + off];
  float cex = fmaxf(re2.x, se2.x) - se2.x;   // relu(re-se)
  float cey = fmaxf(re2.y, se2.y) - se2.y;
  float Kx  = fmaxf(se2.x - re2.x, 0.f);     // relu(se-re)
  float Ky  = fmaxf(se2.y - re2.y, 0.f);
  float amx=0.f, amy=0.f, agx=0.f, agy=0.f, mix=0.f, miy=0.f;
  float hsacc = 0.f;
  float2 A[8], B[8], C[8], D[8];

#define SGB(m,c) __builtin_amdgcn_sched_group_barrier((m),(c),0)

#define LOADB(X, Y, P) { \
  _Pragma("unroll") for (int j=0;j<8;j++){ \
    X[j] = gcp[(unsigned)(((P)+j)*4608)]; \
    Y[j] = gqp[(unsigned)(((P)+j)*4608)]; } }

#define PROCB(X, Y, P) { \
  _Pragma("unroll") for (int j=0;j<8;j++){ \
    float2 g = X[j], h = Y[j]; \
    float sc = stc[(P)+j], sp = stq[(P)+j]; \
    float hmx = fminf(fmaxf(__builtin_fmaf(g.x, 3.5f, -0.35f), 0.f), 1.f); \
    float hmy = fminf(fmaxf(__builtin_fmaf(g.y, 3.5f, -0.35f), 0.f), 1.f); \
    float hpx = fminf(fmaxf(__builtin_fmaf(h.x, 3.5f, -0.35f), 0.f), 1.f); \
    float hpy = fminf(fmaxf(__builtin_fmaf(h.y, 3.5f, -0.35f), 0.f), 1.f); \
    if (nz && ((P)+j)==0) hsacc = hmx + hmy; \
    float ahx = sc*hmx, ahy = sc*hmy; \
    float shx = sp*hpx, shy = sp*hpy; \
    amx += ahx; amy += ahy; \
    agx += g.x; agy += g.y; \
    float Dx = __builtin_fmaf(-se2.x, shx, Kx); \
    float Dy = __builtin_fmaf(-se2.y, shy, Ky); \
    mix += fminf((1.f - ahx)*Dx, 0.f); \
    miy += fminf((1.f - ahy)*Dy, 0.f); } }

  LOADB(A, B, 0)
  SGB(0x20, 16);
  LOADB(C, D, 8)
  SGB(0x20, 16);
  PROCB(A, B, 0)
  SGB(0x2, 256);
  LOADB(A, B, 16)
  SGB(0x20, 16);
  PROCB(C, D, 8)
  SGB(0x2, 256);
  LOADB(C, D, 24)
  SGB(0x20, 16);
  PROCB(A, B, 16)
  SGB(0x2, 256);
  PROCB(C, D, 24)
#undef LOADB
#undef PROCB
#undef SGB

  float qx = 1.f - fminf(amx, 1.f);
  float qy = 1.f - fminf(amy, 1.f);
  float r1 = wred_sum(re2.x*qx + re2.y*qy);
  float r2 = wred_sum(cex*qx + cey*qy);
  float r3 = wred_sum(re2.x + re2.y);
  float r4 = wred_sum(cex + cey);
  float r5 = wred_max(fmaxf(agx, agy));
  float r6 = wred_sum(mix + miy);
  if (lane==0){
    atomicAdd(&melN[n], r1);
    atomicAdd(&mcelN[n], r2);
    atomicAdd(&reS[n], r3);
    atomicAdd(&ceS[n], r4);
    atomicMax(&gmax[n], __float_as_uint(r5));
    atomicAdd(&miS[n], r6);
  }
  if (nz){
    float h = wred_sum(hsacc);
    if (lane==0) atomicAdd(hsG, h);
  }
}

// ---------------- finalization ----------------
__global__ __launch_bounds__(256) void k_final(const float* __restrict__ coords,
                                               const float* __restrict__ status,
                                               const float* __restrict__ miS,
                                               const float* __restrict__ melN,
                                               const float* __restrict__ mcelN,
                                               const float* __restrict__ reS,
                                               const float* __restrict__ ceS,
                                               const unsigned int* __restrict__ gmax,
                                               const float* __restrict__ hsG,
                                               float* __restrict__ out){
  __shared__ float wsum[4];
  int tid = threadIdx.x;
  int n = tid >> 2, q = tid & 3;   // n in 0..63, q selects 8 kp
  int s = n & 3;
  int np = (s==0) ? n+3 : n-1;
  float mc = 0.f, sl = 0.f;
  #pragma unroll
  for (int j=0;j<8;j++){
    int kp = q*8 + j;
    float dx = coords[(n*KPN+kp)*2+0] - coords[(np*KPN+kp)*2+0];
    float dy = coords[(n*KPN+kp)*2+1] - coords[(np*KPN+kp)*2+1];
    float st = status[n*KPN+kp];
    mc += sqrtf(dx*dx+dy*dy) * st * status[np*KPN+kp];
    sl += st;
  }
  mc += __shfl_xor(mc,1,64); mc += __shfl_xor(mc,2,64);
  sl += __shfl_xor(sl,1,64); sl += __shfl_xor(sl,2,64);
  float mint = 0.f;
  if (q==0){
    sl *= (1.f/KPN);
    float rsum = reS[n];
    float mel = melN[n]/(rsum+EPSF);
    float mcel = (s==0) ? 0.f : mcelN[n]/(ceS[n]+EPSF);
    // miS holds M = sum_px sum_kp min((1-ah)D, 0); full mi sum = 32*rsum + M
    // rc = (rsum - (32*rsum + M)/32)/hs = -M/(32*hs)
    float rc = (-miS[n]*(1.f/KPN)) / hsG[0];
    float itl = rc + 0.1f*mc;
    float ovl = fmaxf(__uint_as_float(gmax[n]) - 1.5f, 0.f)*(1.f/KPN);
    mint = 100.f*mel + 100.f*mcel + itl + 10.f*ovl + (1.f-mel)*2.5f*sl;
  }
  float r = wred_sum(mint);
  if ((tid&63)==0) wsum[tid>>6] = r;
  __syncthreads();
  if (tid==0) out[0] = (wsum[0]+wsum[1]+wsum[2]+wsum[3])*(1.f/64.f);
}

extern "C" void kernel_launch(void* const* d_in, const int* in_sizes, int n_in,
                              void* d_out, int out_size, void* d_ws, size_t ws_size,
                              hipStream_t stream){
  const float* coords = (const float*)d_in[0];
  const float* gauss  = (const float*)d_in[1];
  const float* status = (const float*)d_in[2];
  const float* images = (const float*)d_in[3];
  float* out = (float*)d_out;
  float* rimg = (float*)d_ws;                          // 1,769,472 f32
  float* ent  = rimg + (size_t)NIMG*CH*NPIX;           // 589,824 f32
  float* miS  = ent + (size_t)NIMG*NPIX;               // 64
  float* melN = miS + 64;
  float* mcelN = melN + 64;
  float* reS   = mcelN + 64;
  float* ceS   = reS + 64;
  unsigned int* gmax = (unsigned int*)(ceS + 64);      // 64
  float* hsG = (float*)(gmax + 64);                    // 1
  // zero ent (atomicAdd target) + scalar accumulators in one memset
  hipMemsetAsync(ent, 0, ((size_t)NIMG*NPIX + 6*64 + 1)*sizeof(float), stream);
  k_resize<<<(NIMG*CH*NPIX + 255)/256, 256, 0, stream>>>(images, rimg);
  k_entropy<<<dim3(18,64,3), 256, 0, stream>>>(rimg, ent);
  k_main<<<dim3(18,64), 256, 0, stream>>>(gauss, status, ent, miS, melN, mcelN, reS, ceS, gmax, hsG);
  k_final<<<1,256,0,stream>>>(coords, status, miS, melN, mcelN, reS, ceS, gmax, hsG, out);
}

// Round 11
// 112.236 us; speedup vs baseline: 1.0877x; 1.0877x over previous
//
#include <hip/hip_runtime.h>

#define EPSF 1e-10f
#define KPN 32
#define HH 96
#define WW 96
#define NPIX (HH*WW)     // 9216
#define CH 3
#define SH 128
#define SW 128
#define NIMG 64

__device__ inline float wred_sum(float v){
  #pragma unroll
  for(int off=32; off; off>>=1) v += __shfl_xor(v, off, 64);
  return v;
}
__device__ inline float wred_max(float v){
  #pragma unroll
  for(int off=32; off; off>>=1) v = fmaxf(v, __shfl_xor(v, off, 64));
  return v;
}

// ---------------- resize: jax.image.resize bilinear, antialias=True, 128->96 ----------------
__global__ __launch_bounds__(256) void k_resize(const float* __restrict__ img, float* __restrict__ out){
  int idx = blockIdx.x*256 + threadIdx.x;
  if (idx >= NIMG*CH*NPIX) return;
  int ox = idx % WW;
  int oy = (idx / WW) % HH;
  int nc = idx / NPIX;
  float xs = (ox + 0.5f)*(4.0f/3.0f) - 0.5f;
  float ys = (oy + 0.5f)*(4.0f/3.0f) - 0.5f;
  int jx0 = (int)ceilf(xs - 4.0f/3.0f);
  int jy0 = (int)ceilf(ys - 4.0f/3.0f);
  float wx[3], wy[3]; float sx=0.f, sy=0.f;
  #pragma unroll
  for(int t=0;t<3;t++){
    int j = jx0+t;
    float w = 1.0f - 0.75f*fabsf((float)j - xs);
    w = (j>=0 && j<SW) ? fmaxf(w,0.0f) : 0.0f;
    wx[t]=w; sx+=w;
    j = jy0+t;
    w = 1.0f - 0.75f*fabsf((float)j - ys);
    w = (j>=0 && j<SH) ? fmaxf(w,0.0f) : 0.0f;
    wy[t]=w; sy+=w;
  }
  float inv = 1.0f/(sx*sy);
  const float* base = img + (size_t)nc*SH*SW;
  float acc=0.f;
  #pragma unroll
  for(int ty=0;ty<3;ty++){
    if (wy[ty]==0.f) continue;
    int jy = min(max(jy0+ty,0), SH-1);
    #pragma unroll
    for(int tx=0;tx<3;tx++){
      if (wx[tx]==0.f) continue;
      int jx = min(max(jx0+tx,0), SW-1);
      acc += wy[ty]*wx[tx]*base[jy*SW+jx];
    }
  }
  out[idx] = acc*inv;
}

// ---------------- local entropy ----------------
// R8 version (best measured): channel-split, 2x2 outputs/thread, 4x4 reg
// halo, direct per-bin evaluation. (R10's 2x1 retile regressed: 1.5x halo
// loads per output + 2x atomics.) OOB sentinel v=1e4 underflows exp to +0.
__global__ __launch_bounds__(256) void k_entropy(const float* __restrict__ rimg, float* __restrict__ ent){
  int tid = threadIdx.x;
  int n = blockIdx.y;
  int ch = blockIdx.z;
  int idx = blockIdx.x*256 + tid;    // 0..2303
  int rg = idx / 48, cg = idx % 48;
  int r0 = rg*2, c0 = cg*2;
  const float* src = rimg + ((size_t)(n*CH+ch))*NPIX;
  float v[4][4];
  #pragma unroll
  for (int r=0;r<4;r++){
    int gr = r0-1+r;
    bool rok = (gr>=0 && gr<HH);
    #pragma unroll
    for (int c=0;c<4;c++){
      int gc = c0-1+c;
      v[r][c] = (rok && gc>=0 && gc<WW) ? src[gr*96+gc] : 1e4f;
    }
  }
  float S[2][2]={{0.f,0.f},{0.f,0.f}}, T[2][2]={{0.f,0.f},{0.f,0.f}};
  #pragma unroll 4
  for (int b=0;b<16;b++){
    float cb = (float)b * (1.0f/15.0f);
    float k[4][4];
    #pragma unroll
    for (int r=0;r<4;r++)
      #pragma unroll
      for (int c=0;c<4;c++){
        float d = v[r][c] - cb;
        k[r][c] = __expf(-50.f*d*d);
      }
    float vs[2][4];
    #pragma unroll
    for (int rr=0;rr<2;rr++)
      #pragma unroll
      for (int c=0;c<4;c++)
        vs[rr][c] = k[rr][c]+k[rr+1][c]+k[rr+2][c];
    #pragma unroll
    for (int rr=0;rr<2;rr++)
      #pragma unroll
      for (int cc=0;cc<2;cc++){
        float p = (vs[rr][cc]+vs[rr][cc+1]+vs[rr][cc+2])*(1.f/9.f);
        S[rr][cc] += p;
        T[rr][cc] += p*__logf(p+EPSF);
      }
  }
  #pragma unroll
  for (int rr=0;rr<2;rr++)
    #pragma unroll
    for (int cc=0;cc<2;cc++){
      float Sp = S[rr][cc]+EPSF;
      float e = (__logf(Sp) - T[rr][cc]/Sp)*(1.f/3.f);
      atomicAdd(&ent[(size_t)n*NPIX + (size_t)(r0+rr)*96 + (c0+cc)], e);
    }
}

// ---------------- main gaussians pass ----------------
// s-split (block per (tile, n)): 18 waves/CU. R8-R10: at the DEFAULT
// occupancy target the RA caps VGPR at 64 (8 waves/EU) and re-sinks the
// ping-pong loads -> ~2 in flight -> 2.4 TB/s latency ceiling even when
// fully L3-resident. Fix: __launch_bounds__(256, 4) -> 128-VGPR budget
// matching the real 4.5 waves/SIMD grid, so the 64 data VGPRs of the
// ping-pong stay live and 16 loads stay in flight. SGB kept from R10.
// mi folded: mi = re + min((1-ah)*(K - se*sh), 0), K = relu(se-re);
// the 32*re term is recovered in k_final from reS.
__global__ __launch_bounds__(256, 4) void k_main(const float* __restrict__ gauss,
                                              const float* __restrict__ status,
                                              const float* __restrict__ ent,
                                              float* __restrict__ miS,
                                              float* __restrict__ melN,
                                              float* __restrict__ mcelN,
                                              float* __restrict__ reS,
                                              float* __restrict__ ceS,
                                              unsigned int* __restrict__ gmax,
                                              float* __restrict__ hsG){
  __shared__ float stc[32], stq[32];
  int tid = threadIdx.x;
  int lane = tid & 63;
  int tile = blockIdx.x;   // 0..17
  int n = blockIdx.y;      // 0..63 = b*4+s
  int s = n & 3;
  int np = (s==0) ? n+3 : n-1;
  bool nz = (n==0);
  if (tid < 32) stc[tid] = status[n*32 + tid];
  else if (tid < 64) stq[tid-32] = status[np*32 + (tid-32)];
  __syncthreads();
  unsigned off = (unsigned)(tile*256 + tid);     // float2 index within a plane
  const float2* __restrict__ gcp = (const float2*)gauss + (size_t)n*32*4608 + off;
  const float2* __restrict__ gqp = (const float2*)gauss + (size_t)np*32*4608 + off;
  const float2* __restrict__ e2 = (const float2*)ent;
  float2 re2 = e2[(size_t)n*4608 + off];
  float2 se2 = e2[(size_t)np*4608 + off];
  float cex = fmaxf(re2.x, se2.x) - se2.x;   // relu(re-se)
  float cey = fmaxf(re2.y, se2.y) - se2.y;
  float Kx  = fmaxf(se2.x - re2.x, 0.f);     // relu(se-re)
  float Ky  = fmaxf(se2.y - re2.y, 0.f);
  float amx=0.f, amy=0.f, agx=0.f, agy=0.f, mix=0.f, miy=0.f;
  float hsacc = 0.f;
  float2 A[8], B[8], C[8], D[8];

#define SGB(m,c) __builtin_amdgcn_sched_group_barrier((m),(c),0)

#define LOADB(X, Y, P) { \
  _Pragma("unroll") for (int j=0;j<8;j++){ \
    X[j] = gcp[(unsigned)(((P)+j)*4608)]; \
    Y[j] = gqp[(unsigned)(((P)+j)*4608)]; } }

#define PROCB(X, Y, P) { \
  _Pragma("unroll") for (int j=0;j<8;j++){ \
    float2 g = X[j], h = Y[j]; \
    float sc = stc[(P)+j], sp = stq[(P)+j]; \
    float hmx = fminf(fmaxf(__builtin_fmaf(g.x, 3.5f, -0.35f), 0.f), 1.f); \
    float hmy = fminf(fmaxf(__builtin_fmaf(g.y, 3.5f, -0.35f), 0.f), 1.f); \
    float hpx = fminf(fmaxf(__builtin_fmaf(h.x, 3.5f, -0.35f), 0.f), 1.f); \
    float hpy = fminf(fmaxf(__builtin_fmaf(h.y, 3.5f, -0.35f), 0.f), 1.f); \
    if (nz && ((P)+j)==0) hsacc = hmx + hmy; \
    float ahx = sc*hmx, ahy = sc*hmy; \
    float shx = sp*hpx, shy = sp*hpy; \
    amx += ahx; amy += ahy; \
    agx += g.x; agy += g.y; \
    float Dx = __builtin_fmaf(-se2.x, shx, Kx); \
    float Dy = __builtin_fmaf(-se2.y, shy, Ky); \
    mix += fminf((1.f - ahx)*Dx, 0.f); \
    miy += fminf((1.f - ahy)*Dy, 0.f); } }

  LOADB(A, B, 0)
  SGB(0x20, 16);
  LOADB(C, D, 8)
  SGB(0x20, 16);
  PROCB(A, B, 0)
  SGB(0x2, 256);
  LOADB(A, B, 16)
  SGB(0x20, 16);
  PROCB(C, D, 8)
  SGB(0x2, 256);
  LOADB(C, D, 24)
  SGB(0x20, 16);
  PROCB(A, B, 16)
  SGB(0x2, 256);
  PROCB(C, D, 24)
#undef LOADB
#undef PROCB
#undef SGB

  float qx = 1.f - fminf(amx, 1.f);
  float qy = 1.f - fminf(amy, 1.f);
  float r1 = wred_sum(re2.x*qx + re2.y*qy);
  float r2 = wred_sum(cex*qx + cey*qy);
  float r3 = wred_sum(re2.x + re2.y);
  float r4 = wred_sum(cex + cey);
  float r5 = wred_max(fmaxf(agx, agy));
  float r6 = wred_sum(mix + miy);
  if (lane==0){
    atomicAdd(&melN[n], r1);
    atomicAdd(&mcelN[n], r2);
    atomicAdd(&reS[n], r3);
    atomicAdd(&ceS[n], r4);
    atomicMax(&gmax[n], __float_as_uint(r5));
    atomicAdd(&miS[n], r6);
  }
  if (nz){
    float h = wred_sum(hsacc);
    if (lane==0) atomicAdd(hsG, h);
  }
}

// ---------------- finalization ----------------
__global__ __launch_bounds__(256) void k_final(const float* __restrict__ coords,
                                               const float* __restrict__ status,
                                               const float* __restrict__ miS,
                                               const float* __restrict__ melN,
                                               const float* __restrict__ mcelN,
                                               const float* __restrict__ reS,
                                               const float* __restrict__ ceS,
                                               const unsigned int* __restrict__ gmax,
                                               const float* __restrict__ hsG,
                                               float* __restrict__ out){
  __shared__ float wsum[4];
  int tid = threadIdx.x;
  int n = tid >> 2, q = tid & 3;   // n in 0..63, q selects 8 kp
  int s = n & 3;
  int np = (s==0) ? n+3 : n-1;
  float mc = 0.f, sl = 0.f;
  #pragma unroll
  for (int j=0;j<8;j++){
    int kp = q*8 + j;
    float dx = coords[(n*KPN+kp)*2+0] - coords[(np*KPN+kp)*2+0];
    float dy = coords[(n*KPN+kp)*2+1] - coords[(np*KPN+kp)*2+1];
    float st = status[n*KPN+kp];
    mc += sqrtf(dx*dx+dy*dy) * st * status[np*KPN+kp];
    sl += st;
  }
  mc += __shfl_xor(mc,1,64); mc += __shfl_xor(mc,2,64);
  sl += __shfl_xor(sl,1,64); sl += __shfl_xor(sl,2,64);
  float mint = 0.f;
  if (q==0){
    sl *= (1.f/KPN);
    float rsum = reS[n];
    float mel = melN[n]/(rsum+EPSF);
    float mcel = (s==0) ? 0.f : mcelN[n]/(ceS[n]+EPSF);
    // miS holds M = sum_px sum_kp min((1-ah)D, 0); full mi sum = 32*rsum + M
    // rc = (rsum - (32*rsum + M)/32)/hs = -M/(32*hs)
    float rc = (-miS[n]*(1.f/KPN)) / hsG[0];
    float itl = rc + 0.1f*mc;
    float ovl = fmaxf(__uint_as_float(gmax[n]) - 1.5f, 0.f)*(1.f/KPN);
    mint = 100.f*mel + 100.f*mcel + itl + 10.f*ovl + (1.f-mel)*2.5f*sl;
  }
  float r = wred_sum(mint);
  if ((tid&63)==0) wsum[tid>>6] = r;
  __syncthreads();
  if (tid==0) out[0] = (wsum[0]+wsum[1]+wsum[2]+wsum[3])*(1.f/64.f);
}

extern "C" void kernel_launch(void* const* d_in, const int* in_sizes, int n_in,
                              void* d_out, int out_size, void* d_ws, size_t ws_size,
                              hipStream_t stream){
  const float* coords = (const float*)d_in[0];
  const float* gauss  = (const float*)d_in[1];
  const float* status = (const float*)d_in[2];
  const float* images = (const float*)d_in[3];
  float* out = (float*)d_out;
  float* rimg = (float*)d_ws;                          // 1,769,472 f32
  float* ent  = rimg + (size_t)NIMG*CH*NPIX;           // 589,824 f32
  float* miS  = ent + (size_t)NIMG*NPIX;               // 64
  float* melN = miS + 64;
  float* mcelN = melN + 64;
  float* reS   = mcelN + 64;
  float* ceS   = reS + 64;
  unsigned int* gmax = (unsigned int*)(ceS + 64);      // 64
  float* hsG = (float*)(gmax + 64);                    // 1
  // zero ent (atomicAdd target) + scalar accumulators in one memset
  hipMemsetAsync(ent, 0, ((size_t)NIMG*NPIX + 6*64 + 1)*sizeof(float), stream);
  k_resize<<<(NIMG*CH*NPIX + 255)/256, 256, 0, stream>>>(images, rimg);
  k_entropy<<<dim3(9,64,3), 256, 0, stream>>>(rimg, ent);
  k_main<<<dim3(18,64), 256, 0, stream>>>(gauss, status, ent, miS, melN, mcelN, reS, ceS, gmax, hsG);
  k_final<<<1,256,0,stream>>>(coords, status, miS, melN, mcelN, reS, ceS, gmax, hsG, out);
}

// Round 12
// 111.482 us; speedup vs baseline: 1.0951x; 1.0068x over previous
//
#include <hip/hip_runtime.h>

#define EPSF 1e-10f
#define KPN 32
#define HH 96
#define WW 96
#define NPIX (HH*WW)     // 9216
#define CH 3
#define SH 128
#define SW 128
#define NIMG 64

__device__ inline float wred_sum(float v){
  #pragma unroll
  for(int off=32; off; off>>=1) v += __shfl_xor(v, off, 64);
  return v;
}
__device__ inline float wred_max(float v){
  #pragma unroll
  for(int off=32; off; off>>=1) v = fmaxf(v, __shfl_xor(v, off, 64));
  return v;
}

// ---------------- resize: jax.image.resize bilinear, antialias=True, 128->96 ----------------
__global__ __launch_bounds__(256) void k_resize(const float* __restrict__ img, float* __restrict__ out){
  int idx = blockIdx.x*256 + threadIdx.x;
  if (idx >= NIMG*CH*NPIX) return;
  int ox = idx % WW;
  int oy = (idx / WW) % HH;
  int nc = idx / NPIX;
  float xs = (ox + 0.5f)*(4.0f/3.0f) - 0.5f;
  float ys = (oy + 0.5f)*(4.0f/3.0f) - 0.5f;
  int jx0 = (int)ceilf(xs - 4.0f/3.0f);
  int jy0 = (int)ceilf(ys - 4.0f/3.0f);
  float wx[3], wy[3]; float sx=0.f, sy=0.f;
  #pragma unroll
  for(int t=0;t<3;t++){
    int j = jx0+t;
    float w = 1.0f - 0.75f*fabsf((float)j - xs);
    w = (j>=0 && j<SW) ? fmaxf(w,0.0f) : 0.0f;
    wx[t]=w; sx+=w;
    j = jy0+t;
    w = 1.0f - 0.75f*fabsf((float)j - ys);
    w = (j>=0 && j<SH) ? fmaxf(w,0.0f) : 0.0f;
    wy[t]=w; sy+=w;
  }
  float inv = 1.0f/(sx*sy);
  const float* base = img + (size_t)nc*SH*SW;
  float acc=0.f;
  #pragma unroll
  for(int ty=0;ty<3;ty++){
    if (wy[ty]==0.f) continue;
    int jy = min(max(jy0+ty,0), SH-1);
    #pragma unroll
    for(int tx=0;tx<3;tx++){
      if (wx[tx]==0.f) continue;
      int jx = min(max(jx0+tx,0), SW-1);
      acc += wy[ty]*wx[tx]*base[jy*SW+jx];
    }
  }
  out[idx] = acc*inv;
}

// ---------------- local entropy ----------------
// R8 version (best measured): channel-split, 2x2 outputs/thread, 4x4 reg
// halo, direct per-bin evaluation. OOB sentinel v=1e4 underflows exp to +0.
__global__ __launch_bounds__(256) void k_entropy(const float* __restrict__ rimg, float* __restrict__ ent){
  int tid = threadIdx.x;
  int n = blockIdx.y;
  int ch = blockIdx.z;
  int idx = blockIdx.x*256 + tid;    // 0..2303
  int rg = idx / 48, cg = idx % 48;
  int r0 = rg*2, c0 = cg*2;
  const float* src = rimg + ((size_t)(n*CH+ch))*NPIX;
  float v[4][4];
  #pragma unroll
  for (int r=0;r<4;r++){
    int gr = r0-1+r;
    bool rok = (gr>=0 && gr<HH);
    #pragma unroll
    for (int c=0;c<4;c++){
      int gc = c0-1+c;
      v[r][c] = (rok && gc>=0 && gc<WW) ? src[gr*96+gc] : 1e4f;
    }
  }
  float S[2][2]={{0.f,0.f},{0.f,0.f}}, T[2][2]={{0.f,0.f},{0.f,0.f}};
  #pragma unroll 4
  for (int b=0;b<16;b++){
    float cb = (float)b * (1.0f/15.0f);
    float k[4][4];
    #pragma unroll
    for (int r=0;r<4;r++)
      #pragma unroll
      for (int c=0;c<4;c++){
        float d = v[r][c] - cb;
        k[r][c] = __expf(-50.f*d*d);
      }
    float vs[2][4];
    #pragma unroll
    for (int rr=0;rr<2;rr++)
      #pragma unroll
      for (int c=0;c<4;c++)
        vs[rr][c] = k[rr][c]+k[rr+1][c]+k[rr+2][c];
    #pragma unroll
    for (int rr=0;rr<2;rr++)
      #pragma unroll
      for (int cc=0;cc<2;cc++){
        float p = (vs[rr][cc]+vs[rr][cc+1]+vs[rr][cc+2])*(1.f/9.f);
        S[rr][cc] += p;
        T[rr][cc] += p*__logf(p+EPSF);
      }
  }
  #pragma unroll
  for (int rr=0;rr<2;rr++)
    #pragma unroll
    for (int cc=0;cc<2;cc++){
      float Sp = S[rr][cc]+EPSF;
      float e = (__logf(Sp) - T[rr][cc]/Sp)*(1.f/3.f);
      atomicAdd(&ent[(size_t)n*NPIX + (size_t)(r0+rr)*96 + (c0+cc)], e);
    }
}

// ---------------- main gaussians pass ----------------
// s-split (block per (tile, n)). R8-R11 proved the compiler sinks register
// loads to ~2 in flight no matter the source structure (VGPR pinned at 64,
// 2.4 TB/s latency ceiling on L3-resident data). R12: take the schedule
// away from it — asm volatile global_load_dwordx2 (cannot be sunk/reordered)
// in a D=8 ping-pong, counted s_waitcnt vmcnt(N) + sched_barrier(0) fences
// (rule: barrier stops hipcc hoisting consumers above an asm waitcnt).
// 16 loads in flight/wave held in live asm-output registers.
// mi folded: mi = re + min((1-ah)*(K - se*sh), 0), K = relu(se-re);
// the 32*re term is recovered in k_final from reS.
__global__ __launch_bounds__(256, 4) void k_main(const float* __restrict__ gauss,
                                              const float* __restrict__ status,
                                              const float* __restrict__ ent,
                                              float* __restrict__ miS,
                                              float* __restrict__ melN,
                                              float* __restrict__ mcelN,
                                              float* __restrict__ reS,
                                              float* __restrict__ ceS,
                                              unsigned int* __restrict__ gmax,
                                              float* __restrict__ hsG){
  __shared__ float stc[32], stq[32];
  int tid = threadIdx.x;
  int lane = tid & 63;
  int tile = blockIdx.x;   // 0..17
  int n = blockIdx.y;      // 0..63 = b*4+s
  int s = n & 3;
  int np = (s==0) ? n+3 : n-1;
  bool nz = (n==0);
  if (tid < 32) stc[tid] = status[n*32 + tid];
  else if (tid < 64) stq[tid-32] = status[np*32 + (tid-32)];
  __syncthreads();
  unsigned off = (unsigned)(tile*256 + tid);     // float2 index within a plane
  const float2* __restrict__ gc = (const float2*)gauss + (size_t)n*32*4608 + off;
  const float2* __restrict__ gq = (const float2*)gauss + (size_t)np*32*4608 + off;
  const float2* __restrict__ e2 = (const float2*)ent;
  float2 re2 = e2[(size_t)n*4608 + off];
  float2 se2 = e2[(size_t)np*4608 + off];
  float cex = fmaxf(re2.x, se2.x) - se2.x;   // relu(re-se)
  float cey = fmaxf(re2.y, se2.y) - se2.y;
  float Kx  = fmaxf(se2.x - re2.x, 0.f);     // relu(se-re)
  float Ky  = fmaxf(se2.y - re2.y, 0.f);
  float amx=0.f, amy=0.f, agx=0.f, agy=0.f, mix=0.f, miy=0.f;
  float hsacc = 0.f;
  float2 G[8], H[8];

#define GLD(dst, addr) asm volatile("global_load_dwordx2 %0, %1, off" : "=v"(dst) : "v"(addr) : "memory")
#define VMWAIT(N) asm volatile("s_waitcnt vmcnt(" #N ")" ::: "memory")

#define PROC(g, h, KP) { \
  float sc = stc[KP], sp = stq[KP]; \
  float hmx = fminf(fmaxf(__builtin_fmaf((g).x, 3.5f, -0.35f), 0.f), 1.f); \
  float hmy = fminf(fmaxf(__builtin_fmaf((g).y, 3.5f, -0.35f), 0.f), 1.f); \
  float hpx = fminf(fmaxf(__builtin_fmaf((h).x, 3.5f, -0.35f), 0.f), 1.f); \
  float hpy = fminf(fmaxf(__builtin_fmaf((h).y, 3.5f, -0.35f), 0.f), 1.f); \
  if (nz && (KP)==0) hsacc = hmx + hmy; \
  float ahx = sc*hmx, ahy = sc*hmy; \
  float shx = sp*hpx, shy = sp*hpy; \
  amx += ahx; amy += ahy; \
  agx += (g).x; agy += (g).y; \
  float Dx = __builtin_fmaf(-se2.x, shx, Kx); \
  float Dy = __builtin_fmaf(-se2.y, shy, Ky); \
  mix += fminf((1.f - ahx)*Dx, 0.f); \
  miy += fminf((1.f - ahy)*Dy, 0.f); }

#define STEP(I, WN) { \
  VMWAIT(WN); \
  __builtin_amdgcn_sched_barrier(0); \
  PROC(G[(I)&7], H[(I)&7], (I)); \
  if ((I) < 24){ GLD(G[(I)&7], gc + ((I)+8)*4608); GLD(H[(I)&7], gq + ((I)+8)*4608); } \
}

  // fence: ent-load waits stay above the pipeline
  __builtin_amdgcn_sched_barrier(0);
  // prologue: 16 loads in flight
  #pragma unroll
  for (int j=0;j<8;j++){ GLD(G[j], gc + j*4608); GLD(H[j], gq + j*4608); }

  STEP(0,14)  STEP(1,14)  STEP(2,14)  STEP(3,14)
  STEP(4,14)  STEP(5,14)  STEP(6,14)  STEP(7,14)
  STEP(8,14)  STEP(9,14)  STEP(10,14) STEP(11,14)
  STEP(12,14) STEP(13,14) STEP(14,14) STEP(15,14)
  STEP(16,14) STEP(17,14) STEP(18,14) STEP(19,14)
  STEP(20,14) STEP(21,14) STEP(22,14) STEP(23,14)
  STEP(24,14) STEP(25,12) STEP(26,10) STEP(27,8)
  STEP(28,6)  STEP(29,4)  STEP(30,2)  STEP(31,0)

#undef STEP
#undef PROC
#undef VMWAIT
#undef GLD

  float qx = 1.f - fminf(amx, 1.f);
  float qy = 1.f - fminf(amy, 1.f);
  float r1 = wred_sum(re2.x*qx + re2.y*qy);
  float r2 = wred_sum(cex*qx + cey*qy);
  float r3 = wred_sum(re2.x + re2.y);
  float r4 = wred_sum(cex + cey);
  float r5 = wred_max(fmaxf(agx, agy));
  float r6 = wred_sum(mix + miy);
  if (lane==0){
    atomicAdd(&melN[n], r1);
    atomicAdd(&mcelN[n], r2);
    atomicAdd(&reS[n], r3);
    atomicAdd(&ceS[n], r4);
    atomicMax(&gmax[n], __float_as_uint(r5));
    atomicAdd(&miS[n], r6);
  }
  if (nz){
    float h = wred_sum(hsacc);
    if (lane==0) atomicAdd(hsG, h);
  }
}

// ---------------- finalization ----------------
__global__ __launch_bounds__(256) void k_final(const float* __restrict__ coords,
                                               const float* __restrict__ status,
                                               const float* __restrict__ miS,
                                               const float* __restrict__ melN,
                                               const float* __restrict__ mcelN,
                                               const float* __restrict__ reS,
                                               const float* __restrict__ ceS,
                                               const unsigned int* __restrict__ gmax,
                                               const float* __restrict__ hsG,
                                               float* __restrict__ out){
  __shared__ float wsum[4];
  int tid = threadIdx.x;
  int n = tid >> 2, q = tid & 3;   // n in 0..63, q selects 8 kp
  int s = n & 3;
  int np = (s==0) ? n+3 : n-1;
  float mc = 0.f, sl = 0.f;
  #pragma unroll
  for (int j=0;j<8;j++){
    int kp = q*8 + j;
    float dx = coords[(n*KPN+kp)*2+0] - coords[(np*KPN+kp)*2+0];
    float dy = coords[(n*KPN+kp)*2+1] - coords[(np*KPN+kp)*2+1];
    float st = status[n*KPN+kp];
    mc += sqrtf(dx*dx+dy*dy) * st * status[np*KPN+kp];
    sl += st;
  }
  mc += __shfl_xor(mc,1,64); mc += __shfl_xor(mc,2,64);
  sl += __shfl_xor(sl,1,64); sl += __shfl_xor(sl,2,64);
  float mint = 0.f;
  if (q==0){
    sl *= (1.f/KPN);
    float rsum = reS[n];
    float mel = melN[n]/(rsum+EPSF);
    float mcel = (s==0) ? 0.f : mcelN[n]/(ceS[n]+EPSF);
    // miS holds M = sum_px sum_kp min((1-ah)D, 0); full mi sum = 32*rsum + M
    // rc = (rsum - (32*rsum + M)/32)/hs = -M/(32*hs)
    float rc = (-miS[n]*(1.f/KPN)) / hsG[0];
    float itl = rc + 0.1f*mc;
    float ovl = fmaxf(__uint_as_float(gmax[n]) - 1.5f, 0.f)*(1.f/KPN);
    mint = 100.f*mel + 100.f*mcel + itl + 10.f*ovl + (1.f-mel)*2.5f*sl;
  }
  float r = wred_sum(mint);
  if ((tid&63)==0) wsum[tid>>6] = r;
  __syncthreads();
  if (tid==0) out[0] = (wsum[0]+wsum[1]+wsum[2]+wsum[3])*(1.f/64.f);
}

extern "C" void kernel_launch(void* const* d_in, const int* in_sizes, int n_in,
                              void* d_out, int out_size, void* d_ws, size_t ws_size,
                              hipStream_t stream){
  const float* coords = (const float*)d_in[0];
  const float* gauss  = (const float*)d_in[1];
  const float* status = (const float*)d_in[2];
  const float* images = (const float*)d_in[3];
  float* out = (float*)d_out;
  float* rimg = (float*)d_ws;                          // 1,769,472 f32
  float* ent  = rimg + (size_t)NIMG*CH*NPIX;           // 589,824 f32
  float* miS  = ent + (size_t)NIMG*NPIX;               // 64
  float* melN = miS + 64;
  float* mcelN = melN + 64;
  float* reS   = mcelN + 64;
  float* ceS   = reS + 64;
  unsigned int* gmax = (unsigned int*)(ceS + 64);      // 64
  float* hsG = (float*)(gmax + 64);                    // 1
  // zero ent (atomicAdd target) + scalar accumulators in one memset
  hipMemsetAsync(ent, 0, ((size_t)NIMG*NPIX + 6*64 + 1)*sizeof(float), stream);
  k_resize<<<(NIMG*CH*NPIX + 255)/256, 256, 0, stream>>>(images, rimg);
  k_entropy<<<dim3(9,64,3), 256, 0, stream>>>(rimg, ent);
  k_main<<<dim3(18,64), 256, 0, stream>>>(gauss, status, ent, miS, melN, mcelN, reS, ceS, gmax, hsG);
  k_final<<<1,256,0,stream>>>(coords, status, miS, melN, mcelN, reS, ceS, gmax, hsG, out);
}

// Round 13
// 96.088 us; speedup vs baseline: 1.2705x; 1.1602x over previous
//
#include <hip/hip_runtime.h>

#define EPSF 1e-10f
#define KPN 32
#define HH 96
#define WW 96
#define NPIX (HH*WW)     // 9216
#define CH 3
#define SH 128
#define SW 128
#define NIMG 64

__device__ inline float wred_sum(float v){
  #pragma unroll
  for(int off=32; off; off>>=1) v += __shfl_xor(v, off, 64);
  return v;
}
__device__ inline float wred_max(float v){
  #pragma unroll
  for(int off=32; off; off>>=1) v = fmaxf(v, __shfl_xor(v, off, 64));
  return v;
}

// ---------------- resize: jax.image.resize bilinear, antialias=True, 128->96 ----------------
__global__ __launch_bounds__(256) void k_resize(const float* __restrict__ img, float* __restrict__ out){
  int idx = blockIdx.x*256 + threadIdx.x;
  if (idx >= NIMG*CH*NPIX) return;
  int ox = idx % WW;
  int oy = (idx / WW) % HH;
  int nc = idx / NPIX;
  float xs = (ox + 0.5f)*(4.0f/3.0f) - 0.5f;
  float ys = (oy + 0.5f)*(4.0f/3.0f) - 0.5f;
  int jx0 = (int)ceilf(xs - 4.0f/3.0f);
  int jy0 = (int)ceilf(ys - 4.0f/3.0f);
  float wx[3], wy[3]; float sx=0.f, sy=0.f;
  #pragma unroll
  for(int t=0;t<3;t++){
    int j = jx0+t;
    float w = 1.0f - 0.75f*fabsf((float)j - xs);
    w = (j>=0 && j<SW) ? fmaxf(w,0.0f) : 0.0f;
    wx[t]=w; sx+=w;
    j = jy0+t;
    w = 1.0f - 0.75f*fabsf((float)j - ys);
    w = (j>=0 && j<SH) ? fmaxf(w,0.0f) : 0.0f;
    wy[t]=w; sy+=w;
  }
  float inv = 1.0f/(sx*sy);
  const float* base = img + (size_t)nc*SH*SW;
  float acc=0.f;
  #pragma unroll
  for(int ty=0;ty<3;ty++){
    if (wy[ty]==0.f) continue;
    int jy = min(max(jy0+ty,0), SH-1);
    #pragma unroll
    for(int tx=0;tx<3;tx++){
      if (wx[tx]==0.f) continue;
      int jx = min(max(jx0+tx,0), SW-1);
      acc += wy[ty]*wx[tx]*base[jy*SW+jx];
    }
  }
  out[idx] = acc*inv;
}

// ---------------- local entropy ----------------
// Channel-split. Lane owns 3 output cols x 2 output rows (4x3 reg halo);
// horizontal 3-tap shared across lanes via shfl (lane cl covers cols
// 3cl..3cl+2; left/right neighbor colsums come from shfl_up/down, edge
// lanes masked to 0 = the zero pad). Per output: 48 trans vs R8's 80,
// and smaller live state (v[12]+k[12]) -> VGPR ~80 -> better residency.
__global__ __launch_bounds__(256) void k_entropy(const float* __restrict__ rimg, float* __restrict__ ent){
  int tid = threadIdx.x;
  int n = blockIdx.y;
  int ch = blockIdx.z;
  int wave = tid >> 6, lane = tid & 63;
  int half = lane >> 5, cl = lane & 31;
  int rp = wave*2 + half;               // 0..7 row-pair within block
  int r0 = blockIdx.x*16 + rp*2;        // output rows r0, r0+1
  int c0 = cl*3;                        // output cols c0..c0+2
  const float* src = rimg + ((size_t)(n*CH+ch))*NPIX;
  float v[4][3];
  #pragma unroll
  for (int r=0;r<4;r++){
    int gr = r0-1+r;
    bool rok = (gr>=0 && gr<HH);
    #pragma unroll
    for (int c=0;c<3;c++){
      v[r][c] = rok ? src[gr*96 + c0 + c] : 1e4f;
    }
  }
  float S[2][3]={{0,0,0},{0,0,0}}, T[2][3]={{0,0,0},{0,0,0}};
  #pragma unroll
  for (int b=0;b<16;b++){
    float cb = (float)b * (1.0f/15.0f);
    float k[4][3];
    #pragma unroll
    for (int r=0;r<4;r++)
      #pragma unroll
      for (int c=0;c<3;c++){
        float d = v[r][c] - cb;
        k[r][c] = __expf(-50.f*d*d);
      }
    #pragma unroll
    for (int o=0;o<2;o++){
      float cs0 = k[o][0]+k[o+1][0]+k[o+2][0];
      float cs1 = k[o][1]+k[o+1][1]+k[o+2][1];
      float cs2 = k[o][2]+k[o+1][2]+k[o+2][2];
      float lf = __shfl_up(cs2, 1, 64);  if (cl==0)  lf = 0.f;
      float rt = __shfl_down(cs0, 1, 64); if (cl==31) rt = 0.f;
      float p0 = (lf +cs0+cs1)*(1.f/9.f);
      float p1 = (cs0+cs1+cs2)*(1.f/9.f);
      float p2 = (cs1+cs2+rt )*(1.f/9.f);
      S[o][0]+=p0; T[o][0]+=p0*__logf(p0+EPSF);
      S[o][1]+=p1; T[o][1]+=p1*__logf(p1+EPSF);
      S[o][2]+=p2; T[o][2]+=p2*__logf(p2+EPSF);
    }
  }
  #pragma unroll
  for (int o=0;o<2;o++)
    #pragma unroll
    for (int j=0;j<3;j++){
      float Sp = S[o][j]+EPSF;
      float e = (__logf(Sp) - T[o][j]/Sp)*(1.f/3.f);
      atomicAdd(&ent[(size_t)n*NPIX + (size_t)(r0+o)*96 + (c0+j)], e);
    }
}

// ---------------- main gaussians pass ----------------
// s-split + R12 asm pipeline (depth-16 volatile loads, counted vmcnt).
// NEW: XCD-aware block remap. The only data reuse is blocks (t,n) and
// (t,n+1) sharing the prev-s planes; default round-robin puts them on
// different XCDs (private L2s -> reuse missed, 151MB logical hits L3).
// Remap so wgid%8 == n>>3: consecutive-n blocks colocate per XCD, the
// reused chunks L2-hit, L3 traffic ~halves.
__global__ __launch_bounds__(256, 4) void k_main(const float* __restrict__ gauss,
                                              const float* __restrict__ status,
                                              const float* __restrict__ ent,
                                              float* __restrict__ miS,
                                              float* __restrict__ melN,
                                              float* __restrict__ mcelN,
                                              float* __restrict__ reS,
                                              float* __restrict__ ceS,
                                              unsigned int* __restrict__ gmax,
                                              float* __restrict__ hsG){
  __shared__ float stc[32], stq[32];
  int tid = threadIdx.x;
  int lane = tid & 63;
  // XCD decode: wgid%8 = n>>3 (same-XCD for consecutive n within groups of 8)
  int wgid = blockIdx.x;          // 0..1151
  int xcd = wgid & 7;
  int q_ = wgid >> 3;             // 0..143
  int tile = q_ % 18;             // 0..17
  int n = xcd*8 + q_/18;          // 0..63
  int s = n & 3;
  int np = (s==0) ? n+3 : n-1;
  bool nz = (n==0);
  if (tid < 32) stc[tid] = status[n*32 + tid];
  else if (tid < 64) stq[tid-32] = status[np*32 + (tid-32)];
  __syncthreads();
  unsigned off = (unsigned)(tile*256 + tid);     // float2 index within a plane
  const float2* __restrict__ gc = (const float2*)gauss + (size_t)n*32*4608 + off;
  const float2* __restrict__ gq = (const float2*)gauss + (size_t)np*32*4608 + off;
  const float2* __restrict__ e2 = (const float2*)ent;
  float2 re2 = e2[(size_t)n*4608 + off];
  float2 se2 = e2[(size_t)np*4608 + off];
  float cex = fmaxf(re2.x, se2.x) - se2.x;   // relu(re-se)
  float cey = fmaxf(re2.y, se2.y) - se2.y;
  float Kx  = fmaxf(se2.x - re2.x, 0.f);     // relu(se-re)
  float Ky  = fmaxf(se2.y - re2.y, 0.f);
  float amx=0.f, amy=0.f, agx=0.f, agy=0.f, mix=0.f, miy=0.f;
  float hsacc = 0.f;
  float2 G[8], H[8];

#define GLD(dst, addr) asm volatile("global_load_dwordx2 %0, %1, off" : "=v"(dst) : "v"(addr) : "memory")
#define VMWAIT(N) asm volatile("s_waitcnt vmcnt(" #N ")" ::: "memory")

#define PROC(g, h, KP) { \
  float sc = stc[KP], sp = stq[KP]; \
  float hmx = fminf(fmaxf(__builtin_fmaf((g).x, 3.5f, -0.35f), 0.f), 1.f); \
  float hmy = fminf(fmaxf(__builtin_fmaf((g).y, 3.5f, -0.35f), 0.f), 1.f); \
  float hpx = fminf(fmaxf(__builtin_fmaf((h).x, 3.5f, -0.35f), 0.f), 1.f); \
  float hpy = fminf(fmaxf(__builtin_fmaf((h).y, 3.5f, -0.35f), 0.f), 1.f); \
  if (nz && (KP)==0) hsacc = hmx + hmy; \
  float ahx = sc*hmx, ahy = sc*hmy; \
  float shx = sp*hpx, shy = sp*hpy; \
  amx += ahx; amy += ahy; \
  agx += (g).x; agy += (g).y; \
  float Dx = __builtin_fmaf(-se2.x, shx, Kx); \
  float Dy = __builtin_fmaf(-se2.y, shy, Ky); \
  mix += fminf((1.f - ahx)*Dx, 0.f); \
  miy += fminf((1.f - ahy)*Dy, 0.f); }

#define STEP(I, WN) { \
  VMWAIT(WN); \
  __builtin_amdgcn_sched_barrier(0); \
  PROC(G[(I)&7], H[(I)&7], (I)); \
  if ((I) < 24){ GLD(G[(I)&7], gc + ((I)+8)*4608); GLD(H[(I)&7], gq + ((I)+8)*4608); } \
}

  __builtin_amdgcn_sched_barrier(0);
  #pragma unroll
  for (int j=0;j<8;j++){ GLD(G[j], gc + j*4608); GLD(H[j], gq + j*4608); }

  STEP(0,14)  STEP(1,14)  STEP(2,14)  STEP(3,14)
  STEP(4,14)  STEP(5,14)  STEP(6,14)  STEP(7,14)
  STEP(8,14)  STEP(9,14)  STEP(10,14) STEP(11,14)
  STEP(12,14) STEP(13,14) STEP(14,14) STEP(15,14)
  STEP(16,14) STEP(17,14) STEP(18,14) STEP(19,14)
  STEP(20,14) STEP(21,14) STEP(22,14) STEP(23,14)
  STEP(24,14) STEP(25,12) STEP(26,10) STEP(27,8)
  STEP(28,6)  STEP(29,4)  STEP(30,2)  STEP(31,0)

#undef STEP
#undef PROC
#undef VMWAIT
#undef GLD

  float qx = 1.f - fminf(amx, 1.f);
  float qy = 1.f - fminf(amy, 1.f);
  float r1 = wred_sum(re2.x*qx + re2.y*qy);
  float r2 = wred_sum(cex*qx + cey*qy);
  float r3 = wred_sum(re2.x + re2.y);
  float r4 = wred_sum(cex + cey);
  float r5 = wred_max(fmaxf(agx, agy));
  float r6 = wred_sum(mix + miy);
  if (lane==0){
    atomicAdd(&melN[n], r1);
    atomicAdd(&mcelN[n], r2);
    atomicAdd(&reS[n], r3);
    atomicAdd(&ceS[n], r4);
    atomicMax(&gmax[n], __float_as_uint(r5));
    atomicAdd(&miS[n], r6);
  }
  if (nz){
    float h = wred_sum(hsacc);
    if (lane==0) atomicAdd(hsG, h);
  }
}

// ---------------- finalization ----------------
__global__ __launch_bounds__(256) void k_final(const float* __restrict__ coords,
                                               const float* __restrict__ status,
                                               const float* __restrict__ miS,
                                               const float* __restrict__ melN,
                                               const float* __restrict__ mcelN,
                                               const float* __restrict__ reS,
                                               const float* __restrict__ ceS,
                                               const unsigned int* __restrict__ gmax,
                                               const float* __restrict__ hsG,
                                               float* __restrict__ out){
  __shared__ float wsum[4];
  int tid = threadIdx.x;
  int n = tid >> 2, q = tid & 3;   // n in 0..63, q selects 8 kp
  int s = n & 3;
  int np = (s==0) ? n+3 : n-1;
  float mc = 0.f, sl = 0.f;
  #pragma unroll
  for (int j=0;j<8;j++){
    int kp = q*8 + j;
    float dx = coords[(n*KPN+kp)*2+0] - coords[(np*KPN+kp)*2+0];
    float dy = coords[(n*KPN+kp)*2+1] - coords[(np*KPN+kp)*2+1];
    float st = status[n*KPN+kp];
    mc += sqrtf(dx*dx+dy*dy) * st * status[np*KPN+kp];
    sl += st;
  }
  mc += __shfl_xor(mc,1,64); mc += __shfl_xor(mc,2,64);
  sl += __shfl_xor(sl,1,64); sl += __shfl_xor(sl,2,64);
  float mint = 0.f;
  if (q==0){
    sl *= (1.f/KPN);
    float rsum = reS[n];
    float mel = melN[n]/(rsum+EPSF);
    float mcel = (s==0) ? 0.f : mcelN[n]/(ceS[n]+EPSF);
    // miS holds M = sum_px sum_kp min((1-ah)D, 0); full mi sum = 32*rsum + M
    // rc = (rsum - (32*rsum + M)/32)/hs = -M/(32*hs)
    float rc = (-miS[n]*(1.f/KPN)) / hsG[0];
    float itl = rc + 0.1f*mc;
    float ovl = fmaxf(__uint_as_float(gmax[n]) - 1.5f, 0.f)*(1.f/KPN);
    mint = 100.f*mel + 100.f*mcel + itl + 10.f*ovl + (1.f-mel)*2.5f*sl;
  }
  float r = wred_sum(mint);
  if ((tid&63)==0) wsum[tid>>6] = r;
  __syncthreads();
  if (tid==0) out[0] = (wsum[0]+wsum[1]+wsum[2]+wsum[3])*(1.f/64.f);
}

extern "C" void kernel_launch(void* const* d_in, const int* in_sizes, int n_in,
                              void* d_out, int out_size, void* d_ws, size_t ws_size,
                              hipStream_t stream){
  const float* coords = (const float*)d_in[0];
  const float* gauss  = (const float*)d_in[1];
  const float* status = (const float*)d_in[2];
  const float* images = (const float*)d_in[3];
  float* out = (float*)d_out;
  float* rimg = (float*)d_ws;                          // 1,769,472 f32
  float* ent  = rimg + (size_t)NIMG*CH*NPIX;           // 589,824 f32
  float* miS  = ent + (size_t)NIMG*NPIX;               // 64
  float* melN = miS + 64;
  float* mcelN = melN + 64;
  float* reS   = mcelN + 64;
  float* ceS   = reS + 64;
  unsigned int* gmax = (unsigned int*)(ceS + 64);      // 64
  float* hsG = (float*)(gmax + 64);                    // 1
  hipMemsetAsync(ent, 0, ((size_t)NIMG*NPIX + 6*64 + 1)*sizeof(float), stream);
  k_resize<<<(NIMG*CH*NPIX + 255)/256, 256, 0, stream>>>(images, rimg);
  k_entropy<<<dim3(6,64,3), 256, 0, stream>>>(rimg, ent);
  k_main<<<1152, 256, 0, stream>>>(gauss, status, ent, miS, melN, mcelN, reS, ceS, gmax, hsG);
  k_final<<<1,256,0,stream>>>(coords, status, miS, melN, mcelN, reS, ceS, gmax, hsG, out);
}